// Round 14
// baseline (149.922 us; speedup 1.0000x reference)
//
#include <hip/hip_runtime.h>
#include <math.h>

#ifndef M_PI
#define M_PI 3.14159265358979323846
#endif

#define BB     128
#define TT     16384
#define PP     20
#define NCH    18
#define EMIT   512                 // emitted samples per block
#define HIST   160                 // FIR history (0.946^160 tail ~2e-3 effect)
#define WIN    (HIST + EMIT)       // 672 converted rows per block
#define NQ     6                   // K-chunks of 32
#define NTAPS  (HIST + 16)         // 176 taps
#define SFRAGS 86                  // 8-row windows: 672/8=84 + 2 slack
#define OPITCH 516                 // pm stage pitch (u16), even
#define NCHUNK (TT / EMIT)         // 32
#define NTILES 36                  // 32 main (c=0..15) + 4 packed (c=16,17)

typedef float  f32x4v __attribute__((ext_vector_type(4)));
typedef short  bf16x8 __attribute__((ext_vector_type(8)));

struct HTab { float h[NTAPS]; };   // 704 B kernarg

__device__ __forceinline__ uint rne16(float f) {
    uint u = __float_as_uint(f);
    return (u + 0x7fffu + ((u >> 16) & 1u)) >> 16;   // round-nearest-even bf16 bits
}

// shared: vhi frag layout vhi[(s*18 + c)*8 + e], s=row>>3, e=row&7 (16B frags)
__global__ __launch_bounds__(256, 3) void collate_fir(
    const float* __restrict__ x, const float* __restrict__ msk,
    float* __restrict__ out, HTab ht)
{
    __shared__ alignas(16) ushort vhi[SFRAGS * NCH * 8];   // 24768 B
    __shared__ alignas(16) ushort pml[NCH * OPITCH];       // 18576 B
    __shared__ float hlds[NTAPS];                          //   704 B  -> 3 blk/CU

    int tid   = threadIdx.x;
    int blk   = blockIdx.x;
    int chunk = blk & (NCHUNK - 1);
    int b     = blk >> 5;             // blk / NCHUNK
    int t0    = chunk * EMIT;

    // ---- zero slack frags s in [84,86) -----------------------------------
    for (int e = tid; e < 2 * NCH * 8; e += 256)
        vhi[84 * NCH * 8 + e] = 0;

    // ---- h -> LDS: uniform-indexed kernarg reads by thread 0 -------------
    if (tid == 0) {
#pragma unroll
        for (int j = 0; j < NTAPS; ++j) hlds[j] = ht.h[j];
    }

    const float* xb   = x   + (size_t)b * TT * PP;
    const float* mb   = msk + (size_t)b * TT * PP;
    float*       oute = out;
    float*       outm = out + (size_t)BB * NCH * TT;

    constexpr int P1[NCH] = {0,4,5,6,  0,1,2,3,  11,15,16,17, 11,12,13,14, 8,9};
    constexpr int P2[NCH] = {4,5,6,7,  1,2,3,7,  15,16,17,18, 12,13,14,18, 9,10};

    // ---- conversion: 2 rows per unit, packed u32 LDS writes ---------------
    for (int u = tid; u < WIN / 2; u += 256) {
        int r0   = 2 * u;
        int trow = t0 - HIST + r0;          // even; never straddles 0
        float xr0[PP], mr0[PP], xr1[PP], mr1[PP];
        if (trow >= 0) {
            const f32x4v* xp = reinterpret_cast<const f32x4v*>(xb + (size_t)trow * PP);
            const f32x4v* mp = reinterpret_cast<const f32x4v*>(mb + (size_t)trow * PP);
#pragma unroll
            for (int j = 0; j < 5; ++j) {
                f32x4v a0 = xp[j],     m0 = mp[j];
                f32x4v a1 = xp[5 + j], m1 = mp[5 + j];
                xr0[4*j+0]=a0.x; xr0[4*j+1]=a0.y; xr0[4*j+2]=a0.z; xr0[4*j+3]=a0.w;
                mr0[4*j+0]=m0.x; mr0[4*j+1]=m0.y; mr0[4*j+2]=m0.z; mr0[4*j+3]=m0.w;
                xr1[4*j+0]=a1.x; xr1[4*j+1]=a1.y; xr1[4*j+2]=a1.z; xr1[4*j+3]=a1.w;
                mr1[4*j+0]=m1.x; mr1[4*j+1]=m1.y; mr1[4*j+2]=m1.z; mr1[4*j+3]=m1.w;
            }
        } else {
#pragma unroll
            for (int j = 0; j < PP; ++j) { xr0[j]=0.f; mr0[j]=0.f; xr1[j]=0.f; mr1[j]=0.f; }
        }
        int  s  = r0 >> 3;
        int  e  = r0 & 7;                    // even
        bool ep = (r0 >= HIST);
#pragma unroll
        for (int c = 0; c < NCH; ++c) {
            float pm0 = mr0[P1[c]] * mr0[P2[c]];
            float pm1 = mr1[P1[c]] * mr1[P2[c]];
            float v0  = (xr0[P1[c]] - xr0[P2[c]]) * pm0;
            float v1  = (xr1[P1[c]] - xr1[P2[c]]) * pm1;
            *reinterpret_cast<uint*>(&vhi[(s * NCH + c) * 8 + e]) =
                rne16(v0) | (rne16(v1) << 16);
            if (ep)
                *reinterpret_cast<uint*>(&pml[c * OPITCH + (r0 - HIST)]) =
                    rne16(pm0) | (rne16(pm1) << 16);
        }
    }

    __syncthreads();

    // ---- A fragments: Toeplitz h slices, hi/lo bf16, from LDS h -----------
    int lane = tid & 63;
    int wid  = tid >> 6;
    int i16  = lane & 15;
    int g    = lane >> 4;

    bf16x8 Ah[NQ], Al[NQ];
#pragma unroll
    for (int q = 0; q < NQ; ++q) {
#pragma unroll
        for (int e = 0; e < 8; ++e) {
            int   k  = i16 + HIST - 32 * q - (g * 8 + e);
            float hv = (k >= 0 && k < NTAPS) ? hlds[k] : 0.f;
            uint  hh = rne16(hv);
            uint  hl = rne16(hv - __uint_as_float(hh << 16));
            Ah[q][e] = (short)hh;
            Al[q][e] = (short)hl;
        }
    }

    // ---- pm emit: bf16 -> f32, contiguous f32x4 wave stores ---------------
    for (int e = tid; e < NCH * EMIT / 4; e += 256) {      // 2304 quads
        int c  = e >> 7;                    // EMIT/4 = 128 quads per channel
        int tq = e & 127;
        uint2 two = *reinterpret_cast<const uint2*>(&pml[c * OPITCH + 4 * tq]);
        f32x4v o;
        o.x = __uint_as_float((two.x & 0xffffu) << 16);
        o.y = __uint_as_float(two.x & 0xffff0000u);
        o.z = __uint_as_float((two.y & 0xffffu) << 16);
        o.w = __uint_as_float(two.y & 0xffff0000u);
        *reinterpret_cast<f32x4v*>(outm + ((size_t)b * NCH + c) * TT + t0 + 4 * tq) = o;
    }

    // ---- MFMA: 32 main tiles (c=0..15) + 4 packed tiles (c=16,17) ---------
    for (int tile = wid; tile < NTILES; tile += 4) {
        int n = i16;
        int c, Tl;
        if (tile < 32) { c = n;             Tl = tile * 16; }
        else           { c = 16 + (n >> 3); Tl = (tile - 32) * 128 + (n & 7) * 16; }

        f32x4v acc = {0.f, 0.f, 0.f, 0.f};
#pragma unroll
        for (int q = 0; q < NQ; ++q) {
            int sidx = (Tl >> 3) + 4 * q + g;        // 8-row window index (max 85)
            int fo   = (sidx * NCH + c) * 8;
            bf16x8 Bh = *reinterpret_cast<bf16x8*>(&vhi[fo]);
            acc = __builtin_amdgcn_mfma_f32_16x16x32_bf16(Ah[q], Bh, acc, 0, 0, 0);
            acc = __builtin_amdgcn_mfma_f32_16x16x32_bf16(Al[q], Bh, acc, 0, 0, 0);
        }
        // C/D: col = lane&15, row = g*4 + reg -> 4 consecutive output times
        *reinterpret_cast<f32x4v*>(oute + ((size_t)b * NCH + c) * TT + t0 + Tl + g * 4) = acc;
    }
}

extern "C" void kernel_launch(void* const* d_in, const int* in_sizes, int n_in,
                              void* d_out, int out_size, void* d_ws, size_t ws_size,
                              hipStream_t stream)
{
    const float* x = (const float*)d_in[0];
    const float* m = (const float*)d_in[1];
    float* out = (float*)d_out;

    const double sr = 40.0, q = 0.7071067811865476;
    // highpass fc = 0.5
    double w0h = 2.0 * M_PI * 0.5 / sr;
    double alh = sin(w0h) / (2.0 * q), cwh = cos(w0h), a0h = 1.0 + alh;
    double b0h = ((1.0 + cwh) * 0.5) / a0h, b1h = (-(1.0 + cwh)) / a0h, b2h = b0h;
    double a1h = (-2.0 * cwh) / a0h,        a2h = (1.0 - alh) / a0h;
    // lowpass fc = 50
    double w0l = 2.0 * M_PI * 50.0 / sr;
    double all = sin(w0l) / (2.0 * q), cwl = cos(w0l), a0l = 1.0 + all;
    double b0l = ((1.0 - cwl) * 0.5) / a0l, b1l = (1.0 - cwl) / a0l, b2l = b0l;
    double a1l = (-2.0 * cwl) / a0l,        a2l = (1.0 - all) / a0l;

    // impulse response of the cascade, double-precision DF1 (host)
    HTab ht;
    {
        double hx1=0, hx2=0, hy1=0, hy2=0, lx1=0, lx2=0, ly1=0, ly2=0;
        for (int t = 0; t < NTAPS; ++t) {
            double u  = (t == 0) ? 1.0 : 0.0;
            double hy = b0h*u + b1h*hx1 + b2h*hx2 - a1h*hy1 - a2h*hy2;
            hx2 = hx1; hx1 = u;  hy2 = hy1; hy1 = hy;
            double ly = b0l*hy + b1l*lx1 + b2l*lx2 - a1l*ly1 - a2l*ly2;
            lx2 = lx1; lx1 = hy; ly2 = ly1; ly1 = ly;
            ht.h[t] = (float)ly;
        }
    }

    int grid = BB * NCHUNK;   // 4096 blocks: (batch, 512-sample chunk)
    collate_fir<<<grid, 256, 0, stream>>>(x, m, out, ht);
}

// Round 15
// 146.393 us; speedup vs baseline: 1.0241x; 1.0241x over previous
//
#include <hip/hip_runtime.h>
#include <math.h>

#ifndef M_PI
#define M_PI 3.14159265358979323846
#endif

#define BB     128
#define TT     16384
#define PP     20
#define NCH    18
#define EMIT   512                 // emitted samples per block
#define HIST   160                 // FIR history (0.946^160 tail ~2e-3 effect)
#define WIN    (HIST + EMIT)       // 672 converted rows per block
#define H1     416                 // half-1 rows [0,416); half-2 = [416,672)
#define NQ     6                   // K-chunks of 32
#define NTAPS  (HIST + 16)         // 176 taps
#define SFRAGS 86                  // 8-row windows (84 data + 2 zero slack)
#define OPITCH 516                 // pm stage pitch (u16), even
#define NCHUNK (TT / EMIT)         // 32
#define NTILES 36                  // 32 main (c=0..15) + 4 packed (c=16,17)
#define TSPLIT 15                  // tiles 0..14 ready after half-1 (row<=415)

typedef float  f32x4v __attribute__((ext_vector_type(4)));
typedef short  bf16x8 __attribute__((ext_vector_type(8)));

struct HTab { float h[NTAPS]; };   // 704 B kernarg

__device__ __forceinline__ uint rne16(float f) {
    uint u = __float_as_uint(f);
    return (u + 0x7fffu + ((u >> 16) & 1u)) >> 16;   // round-nearest-even bf16 bits
}

// shared: vhi frag layout vhi[(s*18 + c)*8 + e], s=row>>3, e=row&7 (16B frags)
__global__ __launch_bounds__(256, 2) void collate_fir(
    const float* __restrict__ x, const float* __restrict__ msk,
    float* __restrict__ out, HTab ht)
{
    __shared__ alignas(16) ushort vhi[SFRAGS * NCH * 8];   // 24768 B
    __shared__ alignas(16) ushort pml[NCH * OPITCH];       // 18576 B
    __shared__ float hlds[NTAPS];                          //   704 B -> 3 blk/CU

    int tid   = threadIdx.x;
    int blk   = blockIdx.x;
    int chunk = blk & (NCHUNK - 1);
    int b     = blk >> 5;             // blk / NCHUNK
    int t0    = chunk * EMIT;

    // ---- P0: zero slack frags s in [84,86); h -> LDS ---------------------
    for (int e = tid; e < 2 * NCH * 8; e += 256)
        vhi[84 * NCH * 8 + e] = 0;
    if (tid == 0) {
#pragma unroll
        for (int j = 0; j < NTAPS; ++j) hlds[j] = ht.h[j];
    }

    const float* xb   = x   + (size_t)b * TT * PP;
    const float* mb   = msk + (size_t)b * TT * PP;
    float*       oute = out;
    float*       outm = out + (size_t)BB * NCH * TT;

    constexpr int P1[NCH] = {0,4,5,6,  0,1,2,3,  11,15,16,17, 11,12,13,14, 8,9};
    constexpr int P2[NCH] = {4,5,6,7,  1,2,3,7,  15,16,17,18, 12,13,14,18, 9,10};

    // ---- P1: conversion rows [0, H1): 2-row units, packed u32 writes ------
    for (int u = tid; u < H1 / 2; u += 256) {
        int r0   = 2 * u;
        int trow = t0 - HIST + r0;          // even; never straddles 0
        float xr0[PP], mr0[PP], xr1[PP], mr1[PP];
        if (trow >= 0) {
            const f32x4v* xp = reinterpret_cast<const f32x4v*>(xb + (size_t)trow * PP);
            const f32x4v* mp = reinterpret_cast<const f32x4v*>(mb + (size_t)trow * PP);
#pragma unroll
            for (int j = 0; j < 5; ++j) {
                f32x4v a0 = xp[j],     m0 = mp[j];
                f32x4v a1 = xp[5 + j], m1 = mp[5 + j];
                xr0[4*j+0]=a0.x; xr0[4*j+1]=a0.y; xr0[4*j+2]=a0.z; xr0[4*j+3]=a0.w;
                mr0[4*j+0]=m0.x; mr0[4*j+1]=m0.y; mr0[4*j+2]=m0.z; mr0[4*j+3]=m0.w;
                xr1[4*j+0]=a1.x; xr1[4*j+1]=a1.y; xr1[4*j+2]=a1.z; xr1[4*j+3]=a1.w;
                mr1[4*j+0]=m1.x; mr1[4*j+1]=m1.y; mr1[4*j+2]=m1.z; mr1[4*j+3]=m1.w;
            }
        } else {
#pragma unroll
            for (int j = 0; j < PP; ++j) { xr0[j]=0.f; mr0[j]=0.f; xr1[j]=0.f; mr1[j]=0.f; }
        }
        int  s  = r0 >> 3;
        int  e  = r0 & 7;                    // even
        bool ep = (r0 >= HIST);
#pragma unroll
        for (int c = 0; c < NCH; ++c) {
            float pm0 = mr0[P1[c]] * mr0[P2[c]];
            float pm1 = mr1[P1[c]] * mr1[P2[c]];
            float v0  = (xr0[P1[c]] - xr0[P2[c]]) * pm0;
            float v1  = (xr1[P1[c]] - xr1[P2[c]]) * pm1;
            *reinterpret_cast<uint*>(&vhi[(s * NCH + c) * 8 + e]) =
                rne16(v0) | (rne16(v1) << 16);
            if (ep)
                *reinterpret_cast<uint*>(&pml[c * OPITCH + (r0 - HIST)]) =
                    rne16(pm0) | (rne16(pm1) << 16);
        }
    }

    __syncthreads();

    // ---- P3: ISSUE half-2 loads (row = H1 + tid; trow >= 256 always) ------
    int row2  = H1 + tid;                    // 416..671
    int trow2 = t0 - HIST + row2;            // t0 + 256 + tid  (>= 0)
    f32x4v xl[5], ml[5];
    {
        const f32x4v* xp = reinterpret_cast<const f32x4v*>(xb + (size_t)trow2 * PP);
        const f32x4v* mp = reinterpret_cast<const f32x4v*>(mb + (size_t)trow2 * PP);
#pragma unroll
        for (int j = 0; j < 5; ++j) { xl[j] = xp[j]; ml[j] = mp[j]; }
    }

    // ---- P2: A fragments: Toeplitz h slices, hi/lo bf16, from LDS h -------
    int lane = tid & 63;
    int wid  = tid >> 6;
    int i16  = lane & 15;
    int g    = lane >> 4;

    bf16x8 Ah[NQ], Al[NQ];
#pragma unroll
    for (int q = 0; q < NQ; ++q) {
#pragma unroll
        for (int e = 0; e < 8; ++e) {
            int   k  = i16 + HIST - 32 * q - (g * 8 + e);
            float hv = (k >= 0 && k < NTAPS) ? hlds[k] : 0.f;
            uint  hh = rne16(hv);
            uint  hl = rne16(hv - __uint_as_float(hh << 16));
            Ah[q][e] = (short)hh;
            Al[q][e] = (short)hl;
        }
    }

    // ---- P4: MFMA tiles 0..14 (need rows <= 415 only) ---------------------
    for (int tile = wid; tile < TSPLIT; tile += 4) {
        int n = i16;
        int c = n, Tl = tile * 16;
        f32x4v acc = {0.f, 0.f, 0.f, 0.f};
#pragma unroll
        for (int q = 0; q < NQ; ++q) {
            int sidx = (Tl >> 3) + 4 * q + g;
            int fo   = (sidx * NCH + c) * 8;
            bf16x8 Bh = *reinterpret_cast<bf16x8*>(&vhi[fo]);
            acc = __builtin_amdgcn_mfma_f32_16x16x32_bf16(Ah[q], Bh, acc, 0, 0, 0);
            acc = __builtin_amdgcn_mfma_f32_16x16x32_bf16(Al[q], Bh, acc, 0, 0, 0);
        }
        *reinterpret_cast<f32x4v*>(oute + ((size_t)b * NCH + c) * TT + t0 + Tl + g * 4) = acc;
    }

    // ---- P6: pm emit t in [0,256) (written in P1) -------------------------
    for (int e = tid; e < NCH * 64; e += 256) {
        int c  = e >> 6;
        int tq = e & 63;
        uint2 two = *reinterpret_cast<const uint2*>(&pml[c * OPITCH + 4 * tq]);
        f32x4v o;
        o.x = __uint_as_float((two.x & 0xffffu) << 16);
        o.y = __uint_as_float(two.x & 0xffff0000u);
        o.z = __uint_as_float((two.y & 0xffffu) << 16);
        o.w = __uint_as_float(two.y & 0xffff0000u);
        *reinterpret_cast<f32x4v*>(outm + ((size_t)b * NCH + c) * TT + t0 + 4 * tq) = o;
    }

    // ---- P5: consume held loads -> vhi/pml half-2 (s in [52,84)) ----------
    {
        float xr[PP], mr[PP];
#pragma unroll
        for (int j = 0; j < 5; ++j) {
            xr[4*j+0]=xl[j].x; xr[4*j+1]=xl[j].y; xr[4*j+2]=xl[j].z; xr[4*j+3]=xl[j].w;
            mr[4*j+0]=ml[j].x; mr[4*j+1]=ml[j].y; mr[4*j+2]=ml[j].z; mr[4*j+3]=ml[j].w;
        }
        int fb = ((row2 >> 3) * NCH) * 8 + (row2 & 7);
#pragma unroll
        for (int c = 0; c < NCH; ++c) {
            float pm = mr[P1[c]] * mr[P2[c]];
            float v  = (xr[P1[c]] - xr[P2[c]]) * pm;
            vhi[fb + c * 8] = (ushort)rne16(v);
            pml[c * OPITCH + (row2 - HIST)] = (ushort)rne16(pm);
        }
    }

    __syncthreads();

    // ---- P7: pm emit t in [256,512) + MFMA tiles 15..35 -------------------
    for (int e = tid; e < NCH * 64; e += 256) {
        int c  = e >> 6;
        int tq = e & 63;
        uint2 two = *reinterpret_cast<const uint2*>(&pml[c * OPITCH + 256 + 4 * tq]);
        f32x4v o;
        o.x = __uint_as_float((two.x & 0xffffu) << 16);
        o.y = __uint_as_float(two.x & 0xffff0000u);
        o.z = __uint_as_float((two.y & 0xffffu) << 16);
        o.w = __uint_as_float(two.y & 0xffff0000u);
        *reinterpret_cast<f32x4v*>(outm + ((size_t)b * NCH + c) * TT + t0 + 256 + 4 * tq) = o;
    }

    for (int tile = TSPLIT + wid; tile < NTILES; tile += 4) {
        int n = i16;
        int c, Tl;
        if (tile < 32) { c = n;             Tl = tile * 16; }
        else           { c = 16 + (n >> 3); Tl = (tile - 32) * 128 + (n & 7) * 16; }
        f32x4v acc = {0.f, 0.f, 0.f, 0.f};
#pragma unroll
        for (int q = 0; q < NQ; ++q) {
            int sidx = (Tl >> 3) + 4 * q + g;        // max 85 (slack zeroed)
            int fo   = (sidx * NCH + c) * 8;
            bf16x8 Bh = *reinterpret_cast<bf16x8*>(&vhi[fo]);
            acc = __builtin_amdgcn_mfma_f32_16x16x32_bf16(Ah[q], Bh, acc, 0, 0, 0);
            acc = __builtin_amdgcn_mfma_f32_16x16x32_bf16(Al[q], Bh, acc, 0, 0, 0);
        }
        *reinterpret_cast<f32x4v*>(oute + ((size_t)b * NCH + c) * TT + t0 + Tl + g * 4) = acc;
    }
}

extern "C" void kernel_launch(void* const* d_in, const int* in_sizes, int n_in,
                              void* d_out, int out_size, void* d_ws, size_t ws_size,
                              hipStream_t stream)
{
    const float* x = (const float*)d_in[0];
    const float* m = (const float*)d_in[1];
    float* out = (float*)d_out;

    const double sr = 40.0, q = 0.7071067811865476;
    // highpass fc = 0.5
    double w0h = 2.0 * M_PI * 0.5 / sr;
    double alh = sin(w0h) / (2.0 * q), cwh = cos(w0h), a0h = 1.0 + alh;
    double b0h = ((1.0 + cwh) * 0.5) / a0h, b1h = (-(1.0 + cwh)) / a0h, b2h = b0h;
    double a1h = (-2.0 * cwh) / a0h,        a2h = (1.0 - alh) / a0h;
    // lowpass fc = 50
    double w0l = 2.0 * M_PI * 50.0 / sr;
    double all = sin(w0l) / (2.0 * q), cwl = cos(w0l), a0l = 1.0 + all;
    double b0l = ((1.0 - cwl) * 0.5) / a0l, b1l = (1.0 - cwl) / a0l, b2l = b0l;
    double a1l = (-2.0 * cwl) / a0l,        a2l = (1.0 - all) / a0l;

    // impulse response of the cascade, double-precision DF1 (host)
    HTab ht;
    {
        double hx1=0, hx2=0, hy1=0, hy2=0, lx1=0, lx2=0, ly1=0, ly2=0;
        for (int t = 0; t < NTAPS; ++t) {
            double u  = (t == 0) ? 1.0 : 0.0;
            double hy = b0h*u + b1h*hx1 + b2h*hx2 - a1h*hy1 - a2h*hy2;
            hx2 = hx1; hx1 = u;  hy2 = hy1; hy1 = hy;
            double ly = b0l*hy + b1l*lx1 + b2l*lx2 - a1l*ly1 - a2l*ly2;
            lx2 = lx1; lx1 = hy; ly2 = ly1; ly1 = ly;
            ht.h[t] = (float)ly;
        }
    }

    int grid = BB * NCHUNK;   // 4096 blocks: (batch, 512-sample chunk)
    collate_fir<<<grid, 256, 0, stream>>>(x, m, out, ht);
}